// Round 6
// baseline (239.147 us; speedup 1.0000x reference)
//
#include <hip/hip_runtime.h>
#include <math.h>

// Problem constants (from reference setup_inputs)
constexpr int B = 16;
constexpr int S = 4096;
constexpr int F = 512;

constexpr int BLOCK  = 512;               // 8 waves; thread owns one feature f
constexpr int RPB    = 128;               // output rows per block
constexpr int CHUNK  = 16;                // output rows per loop iteration
constexpr int NCHUNK = RPB / CHUNK;       // 8
constexpr int TROWS  = 16;                // rows per staged tile
constexpr int NTILE  = (RPB + 32) / TROWS; // 10 tiles (incl. 16+16 row halo)
constexpr int TILE_FLOATS = TROWS * F;    // 8192 floats = 32 KB
constexpr int SBLK   = S / RPB;           // 32 s-blocks per batch

// Round-6 theory: rounds 2/4/5 all pinned at ~80us / ~3.3 TB/s despite huge
// per-wave MLP and despite FETCH dropping 128->81 MB (R5) -- congestion, not
// starvation. Invariant culprit: per-wave global bursts of 256 B segments at
// 2048 B stride -> each wave's request train hits ~1/8 of L2 banks/channels
// and serializes. Fix: stage CONTIGUOUS 32 KB tiles into LDS via
// global_load_lds (1 KB linear per wave-instr, same shape as the 6.6 TB/s
// fill kernel), transpose implicitly by column reads from LDS (conflict-free:
// bank = lane%32, 2-way aliasing is free). Double-buffered, m201 2-phase
// sync: stage(next) -> compute(cur) -> vmcnt(0) -> s_barrier.

__device__ __forceinline__ void gld_lds16(const float* g, float* l) {
  __builtin_amdgcn_global_load_lds(
      (const __attribute__((address_space(1))) void*)g,
      (__attribute__((address_space(3))) void*)l, 16, 0, 0);
}

// Stage one 16-row x 512-float tile, rows rbase..rbase+15 (clamped = replicate
// pad), into lbase. Half-row h (1 KB) is one wave-instruction: global source
// per-lane (lane*16 B), LDS dest wave-uniform base + lane*16 (HW rule).
// Wave w stages half-rows 4w..4w+3 -> 4 instrs/wave, 32 total.
__device__ __forceinline__ void stage_tile(const float* xb, float* lbase,
                                           int rbase, int wav, int lane) {
#pragma unroll
  for (int i = 0; i < 4; ++i) {
    const int h = wav * 4 + i;            // half-row 0..31
    int r = rbase + (h >> 1);
    r = r < 0 ? 0 : (r > S - 1 ? S - 1 : r);
    const float* g = xb + (size_t)r * F + (h & 1) * 256 + lane * 4;
    gld_lds16(g, lbase + h * 256);
  }
}

__global__ __launch_bounds__(BLOCK) void msavg_kernel(
    const float* __restrict__ x, const float* __restrict__ kw,
    float* __restrict__ out) {
  __shared__ float smem[2 * TILE_FLOATS];   // 64 KB -> 2 blocks/CU

  const int tid  = threadIdx.x;             // = feature f, 0..511
  const int wav  = tid >> 6;
  const int lane = tid & 63;
  const int r0   = blockIdx.x * RPB;        // s-range start
  const int b    = blockIdx.y;

  // softmax over the 4 scale weights, folded with 1/k
  float w0 = kw[0], w1 = kw[1], w2 = kw[2], w3 = kw[3];
  float m  = fmaxf(fmaxf(w0, w1), fmaxf(w2, w3));
  float e0 = expf(w0 - m), e1 = expf(w1 - m), e2 = expf(w2 - m), e3 = expf(w3 - m);
  float inv = 1.0f / (e0 + e1 + e2 + e3);
  const float c3  = e0 * inv * (1.0f / 3.0f);
  const float c7  = e1 * inv * (1.0f / 7.0f);
  const float c15 = e2 * inv * (1.0f / 15.0f);
  const float c31 = e3 * inv * (1.0f / 31.0f);

  const float* xb = x   + (size_t)b * S * F;
  float*       ob = out + (size_t)b * S * F + tid;

  // ---- prologue: tiles 0 (rows r0-16..r0-1) and 1 (rows r0..r0+15) ----
  // tile k covers rows r0-16+16k; tile k lives in buf[k&1].
  stage_tile(xb, smem,               r0 - 16, wav, lane);
  stage_tile(xb, smem + TILE_FLOATS, r0,      wav, lane);
  __builtin_amdgcn_sched_barrier(0);
  asm volatile("s_waitcnt vmcnt(0)" ::: "memory");
  __builtin_amdgcn_s_barrier();
  __builtin_amdgcn_sched_barrier(0);

  // init: prefix rows r0-16..r0+15 -> prev[i] = P[r0-16+i]
  float prev[32];
  {
    float p = 0.0f;
#pragma unroll
    for (int j = 0; j < 32; ++j) {
      p += smem[(j >> 4) * TILE_FLOATS + (j & 15) * F + tid];
      prev[j] = p;
    }
  }
  // all waves done reading buf0/buf1 before buf0 is restaged
  __builtin_amdgcn_sched_barrier(0);
  __builtin_amdgcn_s_barrier();
  __builtin_amdgcn_sched_barrier(0);

  // tile 2 (first compute tile) -> buf0; one-time full drain
  stage_tile(xb, smem, r0 + 16, wav, lane);
  __builtin_amdgcn_sched_barrier(0);
  asm volatile("s_waitcnt vmcnt(0)" ::: "memory");
  __builtin_amdgcn_s_barrier();
  __builtin_amdgcn_sched_barrier(0);

  // ---- main loop: chunk c consumes tile c+2 (buf[c&1]) ----
#pragma unroll
  for (int c = 0; c < NCHUNK; ++c) {
    // stage tile c+3 into buf[(c+3)&1]; in flight during this chunk's compute.
    // Safe: buf[(c+1)&1] held tile c+1, last read in iter c-1 (or init), and
    // the end-of-iter barrier guarantees all waves passed those reads.
    if (c + 3 < NTILE)
      stage_tile(xb, smem + ((c + 3) & 1) * TILE_FLOATS,
                 r0 - 16 + (c + 3) * TROWS, wav, lane);

    // extend prefix from LDS tile: cur[j] = P[T+16+j]
    const float* tb = smem + (c & 1) * TILE_FLOATS;
    float cur[CHUNK];
    {
      float p = prev[31];
#pragma unroll
      for (int j = 0; j < CHUNK; ++j) {
        p += tb[j * F + tid];
        cur[j] = p;
      }
    }

    // emit 16 outputs t = T+j;  W[i] = P[T-16+i] = prev(i<32) / cur(i-32)
    const int T = r0 + c * CHUNK;
#pragma unroll
    for (int j = 0; j < CHUNK; ++j) {
      float Pp1  = (j < 15) ? prev[j + 17] : cur[j - 15];
      float Pp3  = (j < 13) ? prev[j + 19] : cur[j - 13];
      float Pp7  = (j < 9)  ? prev[j + 23] : cur[j - 9];
      float Pp15 = (j < 1)  ? prev[31]     : cur[j - 1];
      float o = c3  * (Pp1  - prev[j + 14]) +
                c7  * (Pp3  - prev[j + 12]) +
                c15 * (Pp7  - prev[j + 8 ]) +
                c31 * (Pp15 - prev[j]);
      ob[(size_t)(T + j) * F] = o;
    }

    // roll the window: prev[i] <- P[T+i]
#pragma unroll
    for (int i = 0; i < 32; ++i)
      prev[i] = (i < CHUNK) ? prev[i + CHUNK] : cur[i - CHUNK];

    // end-of-iter sync: drain stage_{c+3} (+ stores), then barrier.
    // The barrier is what makes next iter's restage of buf[(c+1)&1] safe.
    __builtin_amdgcn_sched_barrier(0);
    asm volatile("s_waitcnt vmcnt(0)" ::: "memory");
    __builtin_amdgcn_s_barrier();
    __builtin_amdgcn_sched_barrier(0);
  }
}

extern "C" void kernel_launch(void* const* d_in, const int* in_sizes, int n_in,
                              void* d_out, int out_size, void* d_ws, size_t ws_size,
                              hipStream_t stream) {
  const float* x  = (const float*)d_in[0];  // [16, 4096, 512] fp32
  const float* kw = (const float*)d_in[1];  // [4] fp32
  float* out = (float*)d_out;               // [16, 4096, 512] fp32
  (void)in_sizes; (void)n_in; (void)out_size; (void)d_ws; (void)ws_size;

  dim3 grid(SBLK, B);  // (32, 16) = 512 blocks, 2 blocks/CU (64 KB LDS each)
  msavg_kernel<<<grid, BLOCK, 0, stream>>>(x, kw, out);
}